// Round 5
// baseline (158.485 us; speedup 1.0000x reference)
//
#include <hip/hip_runtime.h>

#define NEGV -1000000000.0f

// Native vector type (HIP's float4 is a struct; nontemporal builtins
// require a scalar/native-vector pointee).
typedef float f32x4 __attribute__((ext_vector_type(4)));

// x: [B, S, S] fp32, S = 4096. mask = (row < n-1) && (col > row) -> NEGV.
// Grid-stride over rows: 2048 long-lived blocks (8/CU), each processes
// ~16 rows. Avoids per-block launch/retire churn of the 1-row-per-block
// version and keeps many independent loads/stores in flight per wave.
// Per row, exactly nload float4s need a load (prefix up to the diagonal);
// the rest are pure NEG stores with NO load (structural, wave-uniform skip).
__global__ __launch_bounds__(256) void submask_gs_kernel(
    const f32x4* __restrict__ x4,
    f32x4* __restrict__ o4,
    const int* __restrict__ n_ptr,
    int rows_total)
{
    const int n = *n_ptr;                      // uniform scalar
    const f32x4 NEG4 = {NEGV, NEGV, NEGV, NEGV};
    const int t = threadIdx.x;

    for (int rid = blockIdx.x; rid < rows_total; rid += gridDim.x) {
        const int row = rid & 4095;            // row within S x S matrix
        const bool full = (row >= n - 1);      // untouched row: plain copy
        const int nload = full ? 1024 : ((row >> 2) + 1);
        const int sv    = full ? -1   : (row >> 2);   // straddle vec index
        const int rm    = row & 3;             // diagonal position within vec
        const size_t base = (size_t)rid << 10; // 1024 vecs per row

#pragma unroll
        for (int k = 0; k < 4; ++k) {
            const int v = t + (k << 8);
            if (v < nload) {
                f32x4 d = __builtin_nontemporal_load(&x4[base + v]);
                if (v == sv) {
                    // diagonal falls inside this vec: mask past-diagonal comps
                    if (rm < 1) d.y = NEGV;
                    if (rm < 2) d.z = NEGV;
                    if (rm < 3) d.w = NEGV;
                }
                __builtin_nontemporal_store(d, &o4[base + v]);
            } else {
                __builtin_nontemporal_store(NEG4, &o4[base + v]);
            }
        }
    }
}

extern "C" void kernel_launch(void* const* d_in, const int* in_sizes, int n_in,
                              void* d_out, int out_size, void* d_ws, size_t ws_size,
                              hipStream_t stream) {
    const float* x = (const float*)d_in[0];
    const int* n_ptr = (const int*)d_in[1];
    float* out = (float*)d_out;

    const int total = in_sizes[0];             // B * S * S = 134217728
    const int rows_total = total >> 12;        // B * S = 32768 rows of 4096

    const int grid = rows_total < 2048 ? rows_total : 2048;  // 8 blocks/CU

    submask_gs_kernel<<<grid, 256, 0, stream>>>(
        (const f32x4*)x, (f32x4*)out, n_ptr, rows_total);
}

// Round 6
// 145.336 us; speedup vs baseline: 1.0905x; 1.0905x over previous
//
#include <hip/hip_runtime.h>

#define NEGV -1000000000.0f

// Native vector type (HIP's float4 is a struct; nontemporal builtins
// require a scalar/native-vector pointee).
typedef float f32x4 __attribute__((ext_vector_type(4)));

// x: [B, S, S] fp32, S = 4096. mask = (row < n-1) && (col > row) -> NEGV.
// Two phase-pure dispatches, both with R3's one-block-per-row layout
// (consecutive blocks -> consecutive addresses, best DRAM locality):
//   FILL: pure write stream, NEG over the suffix (col > row) of masked rows.
//   COPY: pure 1:1 copy stream, prefix up to the diagonal (+ straddle fixup),
//         full rows for row >= n-1.
// Disjoint vec ranges: COPY owns v < nload, FILL owns v >= nload.

__global__ __launch_bounds__(256) void submask_fill_kernel(
    f32x4* __restrict__ o4,
    const int* __restrict__ n_ptr)
{
    const int n = *n_ptr;
    const int row = blockIdx.x & 4095;
    const bool full = (row >= n - 1);                  // untouched row
    const int nload = full ? 1024 : ((row >> 2) + 1);  // first vec NOT ours
    const size_t base = (size_t)blockIdx.x << 10;
    const f32x4 NEG4 = {NEGV, NEGV, NEGV, NEGV};
    const int t = threadIdx.x;

#pragma unroll
    for (int k = 0; k < 4; ++k) {
        const int v = t + (k << 8);
        if (v >= nload) {
            __builtin_nontemporal_store(NEG4, &o4[base + v]);
        }
    }
}

__global__ __launch_bounds__(256) void submask_copy_kernel(
    const f32x4* __restrict__ x4,
    f32x4* __restrict__ o4,
    const int* __restrict__ n_ptr)
{
    const int n = *n_ptr;
    const int row = blockIdx.x & 4095;
    const bool full = (row >= n - 1);
    const int nload = full ? 1024 : ((row >> 2) + 1);  // vecs needing a load
    const int sv    = full ? -1   : (row >> 2);        // straddle vec index
    const int rm    = row & 3;
    const size_t base = (size_t)blockIdx.x << 10;
    const int t = threadIdx.x;

#pragma unroll
    for (int k = 0; k < 4; ++k) {
        const int v = t + (k << 8);
        if (v < nload) {
            f32x4 d = __builtin_nontemporal_load(&x4[base + v]);
            if (v == sv) {
                // diagonal falls inside this vec: mask past-diagonal comps
                if (rm < 1) d.y = NEGV;
                if (rm < 2) d.z = NEGV;
                if (rm < 3) d.w = NEGV;
            }
            __builtin_nontemporal_store(d, &o4[base + v]);
        }
    }
}

extern "C" void kernel_launch(void* const* d_in, const int* in_sizes, int n_in,
                              void* d_out, int out_size, void* d_ws, size_t ws_size,
                              hipStream_t stream) {
    const float* x = (const float*)d_in[0];
    const int* n_ptr = (const int*)d_in[1];
    float* out = (float*)d_out;

    const int total = in_sizes[0];             // B * S * S = 134217728
    const int rows = total >> 12;              // B * S = 32768 rows of 4096

    submask_fill_kernel<<<rows, 256, 0, stream>>>(
        (f32x4*)out, n_ptr);
    submask_copy_kernel<<<rows, 256, 0, stream>>>(
        (const f32x4*)x, (f32x4*)out, n_ptr);
}

// Round 7
// 145.102 us; speedup vs baseline: 1.0922x; 1.0016x over previous
//
#include <hip/hip_runtime.h>

#define NEGV -1000000000.0f

// Native vector type (HIP's float4 is a struct; nontemporal builtins
// require a scalar/native-vector pointee).
typedef float f32x4 __attribute__((ext_vector_type(4)));

// x: [B, S, S] fp32, S = 4096. mask = (row < n-1) && (col > row) -> NEGV.
// One 256-thread block per row (R3 structure — best so far).
// Loads: nontemporal (use-once stream, don't pollute L2).
// Stores: PLAIN (let L2 aggregate the write stream into full DRAM bursts —
// the harness's fillBuffer kernels reach 6.7-6.8 TB/s with plain stores).
__global__ __launch_bounds__(256) void submask_row_kernel(
    const f32x4* __restrict__ x4,
    f32x4* __restrict__ o4,
    const int* __restrict__ n_ptr)
{
    const int n = *n_ptr;                     // uniform scalar
    const int row = blockIdx.x & 4095;        // row within S x S matrix
    const bool full = (row >= n - 1);         // untouched row: plain copy
    const int nload = full ? 1024 : ((row >> 2) + 1);  // vecs needing a load
    const int sv    = full ? -1   : (row >> 2);        // straddle vec index
    const int rm    = row & 3;                // diagonal position within vec
    const size_t base = (size_t)blockIdx.x << 10;      // 1024 vecs per row
    const f32x4 NEG4 = {NEGV, NEGV, NEGV, NEGV};
    const int t = threadIdx.x;

#pragma unroll
    for (int k = 0; k < 4; ++k) {
        const int v = t + (k << 8);
        if (v < nload) {
            f32x4 d = __builtin_nontemporal_load(&x4[base + v]);
            if (v == sv) {
                // diagonal falls inside this vec: mask past-diagonal comps
                if (rm < 1) d.y = NEGV;
                if (rm < 2) d.z = NEGV;
                if (rm < 3) d.w = NEGV;
            }
            o4[base + v] = d;
        } else {
            o4[base + v] = NEG4;
        }
    }
}

extern "C" void kernel_launch(void* const* d_in, const int* in_sizes, int n_in,
                              void* d_out, int out_size, void* d_ws, size_t ws_size,
                              hipStream_t stream) {
    const float* x = (const float*)d_in[0];
    const int* n_ptr = (const int*)d_in[1];
    float* out = (float*)d_out;

    const int total = in_sizes[0];            // B * S * S = 134217728
    const int rows = total >> 12;             // B * S = 32768 rows of 4096

    submask_row_kernel<<<rows, 256, 0, stream>>>(
        (const f32x4*)x, (f32x4*)out, n_ptr);
}

// Round 8
// 133.426 us; speedup vs baseline: 1.1878x; 1.0875x over previous
//
#include <hip/hip_runtime.h>

#define NEGV -1000000000.0f

// Native vector type (HIP's float4 is a struct; nontemporal builtins
// require a scalar/native-vector pointee).
typedef float f32x4 __attribute__((ext_vector_type(4)));

// x: [B, S, S] fp32, S = 4096. mask = (row < n-1) && (col > row) -> NEGV.
// One 256-thread block per row (R3 structure — best so far).
// Loads: PLAIN (no reuse anywhere, so nt's anti-pollution benefit is nil;
//         testing whether nt-load taxes the L2/L3 read path).
// Stores: NONTEMPORAL (R7 showed plain stores cost ~5 us).
__global__ __launch_bounds__(256) void submask_row_kernel(
    const f32x4* __restrict__ x4,
    f32x4* __restrict__ o4,
    const int* __restrict__ n_ptr)
{
    const int n = *n_ptr;                     // uniform scalar
    const int row = blockIdx.x & 4095;        // row within S x S matrix
    const bool full = (row >= n - 1);         // untouched row: plain copy
    const int nload = full ? 1024 : ((row >> 2) + 1);  // vecs needing a load
    const int sv    = full ? -1   : (row >> 2);        // straddle vec index
    const int rm    = row & 3;                // diagonal position within vec
    const size_t base = (size_t)blockIdx.x << 10;      // 1024 vecs per row
    const f32x4 NEG4 = {NEGV, NEGV, NEGV, NEGV};
    const int t = threadIdx.x;

#pragma unroll
    for (int k = 0; k < 4; ++k) {
        const int v = t + (k << 8);
        if (v < nload) {
            f32x4 d = x4[base + v];
            if (v == sv) {
                // diagonal falls inside this vec: mask past-diagonal comps
                if (rm < 1) d.y = NEGV;
                if (rm < 2) d.z = NEGV;
                if (rm < 3) d.w = NEGV;
            }
            __builtin_nontemporal_store(d, &o4[base + v]);
        } else {
            __builtin_nontemporal_store(NEG4, &o4[base + v]);
        }
    }
}

extern "C" void kernel_launch(void* const* d_in, const int* in_sizes, int n_in,
                              void* d_out, int out_size, void* d_ws, size_t ws_size,
                              hipStream_t stream) {
    const float* x = (const float*)d_in[0];
    const int* n_ptr = (const int*)d_in[1];
    float* out = (float*)d_out;

    const int total = in_sizes[0];            // B * S * S = 134217728
    const int rows = total >> 12;             // B * S = 32768 rows of 4096

    submask_row_kernel<<<rows, 256, 0, stream>>>(
        (const f32x4*)x, (f32x4*)out, n_ptr);
}